// Round 4
// baseline (120.341 us; speedup 1.0000x reference)
//
#include <hip/hip_runtime.h>
#include <hip/hip_bf16.h>

// B=4, Q=K=512, D=512, H=256
#define HH 256
#define DD 512
#define MM 2048                       // B*Q == B*K flattened rows
#define CSCALE 2.8853900817779268f    // 2*log2(e), folded into W (linear)

typedef __bf16 bf16x8 __attribute__((ext_vector_type(8)));
typedef float floatx4 __attribute__((ext_vector_type(4)));
typedef float float2v __attribute__((ext_vector_type(2)));

// ---------------------------------------------------------------------------
// prep: (a) transpose+scale Wq,Wk (512x256 f32) -> Wt[2][256][512] bf16
//       (b) wv2 = -2*wv; wsum2[hq] = (-2(w0+w2), -2(w1+w3)); sumW = sum(wv)
// ---------------------------------------------------------------------------
__global__ __launch_bounds__(256) void prep_kernel(
    const float* __restrict__ Wq, const float* __restrict__ Wk,
    const float* __restrict__ wv,
    __bf16* __restrict__ Wt, float* __restrict__ wv2,
    float2v* __restrict__ wsum2, float* __restrict__ sumWp)
{
  const int bx = blockIdx.x;
  if (bx < 256) {
    const int mat  = bx >> 7;
    const int tile = bx & 127;
    const int kt = tile & 15;    // 512/32 k-tiles
    const int nt = tile >> 4;    // 256/32 n-tiles
    const float* __restrict__ W = mat ? Wk : Wq;
    __bf16* __restrict__ Wo = Wt + (size_t)mat * HH * DD;
    __shared__ float lds[32][33];
    const int i = threadIdx.x >> 5;   // 0..7
    const int j = threadIdx.x & 31;   // 0..31
    const int k0 = kt * 32, n0 = nt * 32;
#pragma unroll
    for (int p = 0; p < 4; ++p)
      lds[i + p * 8][j] = W[(k0 + i + p * 8) * HH + n0 + j];
    __syncthreads();
#pragma unroll
    for (int p = 0; p < 4; ++p) {
      const int n = i + p * 8;
      Wo[(n0 + n) * DD + k0 + j] = (__bf16)(lds[j][n] * CSCALE);
    }
  } else {
    __shared__ float red[256];
    const int t = threadIdx.x;
    float w = wv[t];
    wv2[t] = -2.0f * w;
    if (t < 64) {
      float2v ws;
      ws.x = -2.0f * (wv[4 * t + 0] + wv[4 * t + 2]);
      ws.y = -2.0f * (wv[4 * t + 1] + wv[4 * t + 3]);
      wsum2[t] = ws;
    }
    red[t] = w;
    __syncthreads();
    for (int s = 128; s > 0; s >>= 1) {
      if (t < s) red[t] += red[t + s];
      __syncthreads();
    }
    if (t == 0) *sumWp = red[0];
  }
}

// ---------------------------------------------------------------------------
// proj: P = X(2048x512 f32) @ Wt^T (bf16, prescaled by 2*log2e).
// Epilogue applies exp2:
//   z==0: queries -> eq = exp2(qc) f32 [2048][256] row-major (SMEM-friendly)
//   z==1: keys    -> ek = exp2(kc) f32 [64][2048][4] (h-quad packed)
// Fragment layouts (HW-verified rounds 1-3):
//   A: lane A[m=lane&15][k=(lane>>4)*8+j]; B: B[k=(lane>>4)*8+j][n=lane&15]
//   D: reg i -> row=(lane>>4)*4+i, col=lane&15
// ---------------------------------------------------------------------------
__global__ __launch_bounds__(256) void proj_kernel(
    const float* __restrict__ queries, const float* __restrict__ keys,
    const __bf16* __restrict__ Wt,
    float* __restrict__ eqp, float* __restrict__ ekp)
{
  const int w    = threadIdx.x >> 6;
  const int lane = threadIdx.x & 63;
  const int quad = lane >> 4;
  const int r    = lane & 15;
  const bool is_k = (blockIdx.z != 0);
  const float* __restrict__ X = is_k ? keys : queries;
  const __bf16* __restrict__ Wb = Wt + (is_k ? (size_t)HH * DD : 0);

  const int m0 = blockIdx.x * 32 + (w >> 1) * 16;
  const int n0 = blockIdx.y * 64 + (w & 1) * 32;

  floatx4 acc0 = {0.f, 0.f, 0.f, 0.f};
  floatx4 acc1 = {0.f, 0.f, 0.f, 0.f};
  const float* arow = X + (size_t)(m0 + r) * DD + quad * 8;
  const __bf16* b0 = Wb + (size_t)(n0 + r) * DD + quad * 8;
  const __bf16* b1 = b0 + 16 * DD;

  for (int kk = 0; kk < DD; kk += 32) {
    float4 a0 = *(const float4*)(arow + kk);
    float4 a1 = *(const float4*)(arow + kk + 4);
    bf16x8 af;
    af[0] = (__bf16)a0.x; af[1] = (__bf16)a0.y;
    af[2] = (__bf16)a0.z; af[3] = (__bf16)a0.w;
    af[4] = (__bf16)a1.x; af[5] = (__bf16)a1.y;
    af[6] = (__bf16)a1.z; af[7] = (__bf16)a1.w;
    bf16x8 bf0 = *(const bf16x8*)(b0 + kk);
    bf16x8 bf1 = *(const bf16x8*)(b1 + kk);
    acc0 = __builtin_amdgcn_mfma_f32_16x16x32_bf16(af, bf0, acc0, 0, 0, 0);
    acc1 = __builtin_amdgcn_mfma_f32_16x16x32_bf16(af, bf1, acc1, 0, 0, 0);
  }

  const int mrow = m0 + quad * 4;
  if (!is_k) {
#pragma unroll
    for (int i = 0; i < 4; ++i) {
      eqp[(size_t)(mrow + i) * HH + n0 + r] =
          __builtin_amdgcn_exp2f(acc0[i]);
      eqp[(size_t)(mrow + i) * HH + n0 + 16 + r] =
          __builtin_amdgcn_exp2f(acc1[i]);
    }
  } else {
#pragma unroll
    for (int i = 0; i < 4; ++i) {
      int na = n0 + r, nb = n0 + 16 + r;
      ekp[((size_t)(na >> 2) * MM + (mrow + i)) * 4 + (na & 3)] =
          __builtin_amdgcn_exp2f(acc0[i]);
      ekp[((size_t)(nb >> 2) * MM + (mrow + i)) * 4 + (nb & 3)] =
          __builtin_amdgcn_exp2f(acc1[i]);
    }
  }
}

// ---------------------------------------------------------------------------
// score: out[b,q,k] = sumW + sum_h wv2[h] * rcp(1 + eq[q,h]*ek[k,h])
// Paired-rcp form, two h per division (pairs (h0,h2),(h1,h3) of each quad):
//   w0/d0 + w2/d2 = [(w0+w2) + w0*p2 + w2*p0] * rcp(1 + (p0+p2) + p0*p2)
// All pair math in float2 ext-vectors -> v_pk_{mul,add,fma}_f32 (gfx950
// packed fp32). Per 4 terms: 8 packed VALU + 2 rcp = ~8 issue-cyc/wave-term.
// eq rows + w constants wave-uniform (s_load path); ek one dwordx4 / 4h.
// grid (2,256,4)=2048 blocks, TQ=2.
// ---------------------------------------------------------------------------
__device__ __forceinline__ float2v pair_step(
    float2v eq01, float2v eq23, float2v ek01, float2v ek23,
    float2v Wlo, float2v Whi, float2v Ws, float2v acc)
{
  float2v Pl = eq01 * ek01;                       // (p0, p1)
  float2v Ph = eq23 * ek23;                       // (p2, p3)
  float2v s  = Pl + Ph;                           // (p0+p2, p1+p3)
  float2v tt = __builtin_elementwise_fma(Pl, Ph, s);
  float2v d  = tt + (float2v){1.0f, 1.0f};        // (d0*d2, d1*d3)
  float2v n  = __builtin_elementwise_fma(Wlo, Ph, Ws);
  n          = __builtin_elementwise_fma(Whi, Pl, n);
  float2v r  = {__builtin_amdgcn_rcpf(d.x), __builtin_amdgcn_rcpf(d.y)};
  return __builtin_elementwise_fma(n, r, acc);
}

__global__ __launch_bounds__(256) void score_kernel(
    const float* __restrict__ eqp, const float4* __restrict__ ekp,
    const float4* __restrict__ wv2, const float2v* __restrict__ wsum2,
    const float* __restrict__ sumWp, float* __restrict__ out)
{
  const int t  = threadIdx.x;
  const int b  = blockIdx.z;
  const int k  = blockIdx.x * 256 + t;
  const int q0 = blockIdx.y * 2;
  const float sumW = *sumWp;

  const float4* __restrict__ kptr = ekp + (size_t)b * 512 + k;
  const float2v* __restrict__ qrow0 =
      (const float2v*)(eqp + (size_t)(b * 512 + q0) * HH);
  const float2v* __restrict__ qrow1 = qrow0 + HH / 2;

  float2v acc0 = {0.f, 0.f}, acc1 = {0.f, 0.f};

#pragma unroll 8
  for (int hq = 0; hq < 64; ++hq) {
    float4 ek4 = kptr[(size_t)hq * MM];
    float2v ek01 = {ek4.x, ek4.y};
    float2v ek23 = {ek4.z, ek4.w};
    float4 w4 = wv2[hq];
    float2v Wlo = {w4.x, w4.y};
    float2v Whi = {w4.z, w4.w};
    float2v Ws  = wsum2[hq];
    float2v eq01a = qrow0[hq * 2], eq23a = qrow0[hq * 2 + 1];
    float2v eq01b = qrow1[hq * 2], eq23b = qrow1[hq * 2 + 1];
    acc0 = pair_step(eq01a, eq23a, ek01, ek23, Wlo, Whi, Ws, acc0);
    acc1 = pair_step(eq01b, eq23b, ek01, ek23, Wlo, Whi, Ws, acc1);
  }

  const size_t obase = ((size_t)b * 512 + q0) * 512 + blockIdx.x * 256 + t;
  out[obase]       = sumW + acc0.x + acc0.y;
  out[obase + 512] = sumW + acc1.x + acc1.y;
}

// ---------------------------------------------------------------------------
extern "C" void kernel_launch(void* const* d_in, const int* in_sizes, int n_in,
                              void* d_out, int out_size, void* d_ws, size_t ws_size,
                              hipStream_t stream) {
  (void)in_sizes; (void)n_in; (void)out_size; (void)ws_size;
  const float* queries = (const float*)d_in[0];
  const float* keys    = (const float*)d_in[1];
  const float* Wq      = (const float*)d_in[2];
  const float* Wk      = (const float*)d_in[3];
  const float* wv      = (const float*)d_in[4];
  float* out = (float*)d_out;

  // ws layout (ws is 256 MB; we use 5 MB):
  //   [0, 512K)      Wt    bf16 [2][256][512]
  //   [512K, +1K)    wv2   f32 [256]
  //   [513K, +512)   wsum2 f32x2 [64]
  //   [514K, +4)     sumW
  //   [1M, 3M)       eq    f32 [2048][256]
  //   [3M, 5M)       ek    f32 [64][2048][4]
  char* ws = (char*)d_ws;
  __bf16*  Wt    = (__bf16*)ws;
  float*   wv2   = (float*)(ws + (512 << 10));
  float2v* wsum2 = (float2v*)(ws + (513 << 10));
  float*   sumWp = (float*)(ws + (514 << 10));
  float*   eqp   = (float*)(ws + (1 << 20));
  float*   ekp   = (float*)(ws + (3 << 20));

  prep_kernel<<<dim3(257), 256, 0, stream>>>(Wq, Wk, wv, Wt, wv2, wsum2, sumWp);
  proj_kernel<<<dim3(64, 4, 2), 256, 0, stream>>>(queries, keys, Wt, eqp, ekp);
  score_kernel<<<dim3(2, 256, 4), 256, 0, stream>>>(
      eqp, (const float4*)ekp, (const float4*)wv2, wsum2, sumWp, out);
}

// Round 5
// 118.186 us; speedup vs baseline: 1.0182x; 1.0182x over previous
//
#include <hip/hip_runtime.h>
#include <hip/hip_bf16.h>

// B=4, Q=K=512, D=512, H=256
#define HH 256
#define DD 512
#define MM 2048                       // B*Q == B*K flattened rows
#define CSCALE 2.8853900817779268f    // 2*log2(e), folded into W (linear)

typedef __bf16 bf16x8 __attribute__((ext_vector_type(8)));
typedef float floatx4 __attribute__((ext_vector_type(4)));

// ---------------------------------------------------------------------------
// prep: (a) blocks 0..255: transpose+scale Wq,Wk -> Wt[2][256][512] bf16
//       (b) block 256: wv2 = -2*wv, sumW = sum(wv)
//       (c) blocks 257..1280: convert queries||keys f32 -> Xbf bf16 [2M]
// ---------------------------------------------------------------------------
__global__ __launch_bounds__(256) void prep_kernel(
    const float* __restrict__ Wq, const float* __restrict__ Wk,
    const float* __restrict__ wv,
    const float* __restrict__ queries, const float* __restrict__ keys,
    __bf16* __restrict__ Wt, __bf16* __restrict__ Xbf,
    float* __restrict__ wv2, float* __restrict__ sumWp)
{
  const int bx = blockIdx.x;
  if (bx < 256) {
    const int mat  = bx >> 7;
    const int tile = bx & 127;
    const int kt = tile & 15;    // 512/32 k-tiles
    const int nt = tile >> 4;    // 256/32 n-tiles
    const float* __restrict__ W = mat ? Wk : Wq;
    __bf16* __restrict__ Wo = Wt + (size_t)mat * HH * DD;
    __shared__ float lds[32][33];
    const int i = threadIdx.x >> 5;   // 0..7
    const int j = threadIdx.x & 31;   // 0..31
    const int k0 = kt * 32, n0 = nt * 32;
#pragma unroll
    for (int p = 0; p < 4; ++p)
      lds[i + p * 8][j] = W[(k0 + i + p * 8) * HH + n0 + j];
    __syncthreads();
#pragma unroll
    for (int p = 0; p < 4; ++p) {
      const int n = i + p * 8;
      Wo[(n0 + n) * DD + k0 + j] = (__bf16)(lds[j][n] * CSCALE);
    }
  } else if (bx == 256) {
    __shared__ float red[256];
    const int t = threadIdx.x;
    float w = wv[t];
    wv2[t] = -2.0f * w;
    red[t] = w;
    __syncthreads();
    for (int s = 128; s > 0; s >>= 1) {
      if (t < s) red[t] += red[t + s];
      __syncthreads();
    }
    if (t == 0) *sumWp = red[0];
  } else {
    const int blk = bx - 257;                       // 0..1023
    const size_t dst = (size_t)blk * 2048 + threadIdx.x * 8;
    const float* __restrict__ src =
        (blk < 512) ? (queries + dst) : (keys + dst - (size_t)1048576);
    float4 a = *(const float4*)(src);
    float4 b = *(const float4*)(src + 4);
    bf16x8 v;
    v[0] = (__bf16)a.x; v[1] = (__bf16)a.y; v[2] = (__bf16)a.z; v[3] = (__bf16)a.w;
    v[4] = (__bf16)b.x; v[5] = (__bf16)b.y; v[6] = (__bf16)b.z; v[7] = (__bf16)b.w;
    *(bf16x8*)(Xbf + dst) = v;
  }
}

// ---------------------------------------------------------------------------
// proj: P = Xbf(2048x512 bf16) @ Wt^T (bf16, prescaled by 2*log2e).
// Block = 4 waves: wave (tw, ks) computes 16x32 tile tw over K-half ks.
// K-split-2 doubles wave count (4096 waves = 4/SIMD) vs round 4's 2/SIMD.
// LDS combine, then exp2 epilogue:
//   z==0: queries -> eq = exp2(qc) f32 [2048][256]
//   z==1: keys    -> ek = exp2(kc) f32 [64][2048][4] (h-quad packed)
// Fragment layouts (HW-verified rounds 1-4):
//   A: lane A[m=lane&15][k=(lane>>4)*8+j]; B: B[k=(lane>>4)*8+j][n=lane&15]
//   D: reg i -> row=(lane>>4)*4+i, col=lane&15
// ---------------------------------------------------------------------------
__global__ __launch_bounds__(256, 4) void proj_kernel(
    const __bf16* __restrict__ Xbf, const __bf16* __restrict__ Wt,
    float* __restrict__ eqp, float* __restrict__ ekp)
{
  const int w    = threadIdx.x >> 6;
  const int lane = threadIdx.x & 63;
  const int quad = lane >> 4;
  const int r    = lane & 15;
  const int tw = w & 1;        // which 16-row tile
  const int ks = w >> 1;       // which K half
  const bool is_k = (blockIdx.z != 0);
  const __bf16* __restrict__ X  = Xbf + (is_k ? (size_t)1048576 : 0);
  const __bf16* __restrict__ Wb = Wt + (is_k ? (size_t)HH * DD : 0);

  const int m0 = blockIdx.x * 32 + tw * 16;
  const int n0 = blockIdx.y * 32;

  floatx4 acc0 = {0.f, 0.f, 0.f, 0.f};
  floatx4 acc1 = {0.f, 0.f, 0.f, 0.f};
  const __bf16* arow = X + (size_t)(m0 + r) * DD + ks * 256 + quad * 8;
  const __bf16* b0   = Wb + (size_t)(n0 + r) * DD + ks * 256 + quad * 8;
  const __bf16* b1   = b0 + 16 * DD;

#pragma unroll
  for (int kk = 0; kk < 256; kk += 32) {
    bf16x8 af  = *(const bf16x8*)(arow + kk);
    bf16x8 bf0 = *(const bf16x8*)(b0 + kk);
    bf16x8 bf1 = *(const bf16x8*)(b1 + kk);
    acc0 = __builtin_amdgcn_mfma_f32_16x16x32_bf16(af, bf0, acc0, 0, 0, 0);
    acc1 = __builtin_amdgcn_mfma_f32_16x16x32_bf16(af, bf1, acc1, 0, 0, 0);
  }

  __shared__ float part[2][64][9];   // +1 pad: conflict-free combine
  if (ks == 1) {
#pragma unroll
    for (int i = 0; i < 4; ++i) {
      part[tw][lane][i]     = acc0[i];
      part[tw][lane][4 + i] = acc1[i];
    }
  }
  __syncthreads();
  if (ks == 0) {
#pragma unroll
    for (int i = 0; i < 4; ++i) {
      acc0[i] += part[tw][lane][i];
      acc1[i] += part[tw][lane][4 + i];
    }
    const int mrow = m0 + quad * 4;
    if (!is_k) {
#pragma unroll
      for (int i = 0; i < 4; ++i) {
        eqp[(size_t)(mrow + i) * HH + n0 + r] =
            __builtin_amdgcn_exp2f(acc0[i]);
        eqp[(size_t)(mrow + i) * HH + n0 + 16 + r] =
            __builtin_amdgcn_exp2f(acc1[i]);
      }
    } else {
      const int na = n0 + r, nb = n0 + 16 + r;
#pragma unroll
      for (int i = 0; i < 4; ++i) {
        ekp[((size_t)(na >> 2) * MM + (mrow + i)) * 4 + (na & 3)] =
            __builtin_amdgcn_exp2f(acc0[i]);
        ekp[((size_t)(nb >> 2) * MM + (mrow + i)) * 4 + (nb & 3)] =
            __builtin_amdgcn_exp2f(acc1[i]);
      }
    }
  }
}

// ---------------------------------------------------------------------------
// score: out[b,q,k] = sumW + sum_pairs (w0'*u2 + w2'*u0) * rcp(u0*u2)
//   u_i = 1 + eq[q,h_i]*ek[k,h_i], w' = -2w  (== sum_h wv[h]*tanh(q+k))
// Pairs (h0,h2),(h1,h3) per quad; one rcp per 2 h. Scalar-operand discipline:
// eq and w' are wave-uniform (s_load path), each VALU op has <=1 SGPR operand.
// 6 VALU + 1 trans per 2 terms = 10 issue-cyc/wave-term. TQ=4 q-rows per
// thread (halves ek L2 traffic vs TQ=2). grid (2,128,4)=1024 blocks.
// ---------------------------------------------------------------------------
__global__ __launch_bounds__(256, 4) void score_kernel(
    const float* __restrict__ eqp, const float4* __restrict__ ekp,
    const float* __restrict__ wv2, const float* __restrict__ sumWp,
    float* __restrict__ out)
{
  const int t  = threadIdx.x;
  const int b  = blockIdx.z;
  const int k  = blockIdx.x * 256 + t;
  const int q0 = blockIdx.y * 4;
  const float sumW = *sumWp;

  const float4* __restrict__ kptr = ekp + (size_t)b * 512 + k;
  const float* __restrict__ qb = eqp + (size_t)(b * 512 + q0) * HH;

  float acc[4] = {0.f, 0.f, 0.f, 0.f};

#pragma unroll 4
  for (int hq = 0; hq < 64; ++hq) {
    float4 ek4 = kptr[(size_t)hq * MM];
    const float* wq = wv2 + hq * 4;             // uniform -> s_load
    float w0 = wq[0], w1 = wq[1], w2 = wq[2], w3 = wq[3];
#pragma unroll
    for (int qi = 0; qi < 4; ++qi) {
      const float* eqr = qb + qi * HH + hq * 4; // uniform -> s_load
      float e0 = eqr[0], e1 = eqr[1], e2 = eqr[2], e3 = eqr[3];
      float u0 = fmaf(e0, ek4.x, 1.0f);
      float u1 = fmaf(e1, ek4.y, 1.0f);
      float u2 = fmaf(e2, ek4.z, 1.0f);
      float u3 = fmaf(e3, ek4.w, 1.0f);
      float n02 = fmaf(w2, u0, w0 * u2);
      float n13 = fmaf(w3, u1, w1 * u3);
      float r02 = __builtin_amdgcn_rcpf(u0 * u2);
      float r13 = __builtin_amdgcn_rcpf(u1 * u3);
      acc[qi] = fmaf(n02, r02, acc[qi]);
      acc[qi] = fmaf(n13, r13, acc[qi]);
    }
  }

  const size_t ob = ((size_t)(b * 512 + q0)) * 512 + blockIdx.x * 256 + t;
  out[ob]        = sumW + acc[0];
  out[ob + 512]  = sumW + acc[1];
  out[ob + 1024] = sumW + acc[2];
  out[ob + 1536] = sumW + acc[3];
}

// ---------------------------------------------------------------------------
extern "C" void kernel_launch(void* const* d_in, const int* in_sizes, int n_in,
                              void* d_out, int out_size, void* d_ws, size_t ws_size,
                              hipStream_t stream) {
  (void)in_sizes; (void)n_in; (void)out_size; (void)ws_size;
  const float* queries = (const float*)d_in[0];
  const float* Keys    = (const float*)d_in[1];
  const float* Wq      = (const float*)d_in[2];
  const float* Wk      = (const float*)d_in[3];
  const float* wv      = (const float*)d_in[4];
  float* out = (float*)d_out;

  // ws layout (~9 MB of the 256 MB workspace):
  //   [0, 512K)      Wt   bf16 [2][256][512]
  //   [512K, +1K)    wv2  f32 [256]  (= -2*wv)
  //   [513K, +4)     sumW
  //   [1M, 5M)       Xbf  bf16 [2][2048][512]  (queries||keys, converted)
  //   [5M, 7M)       eq   f32 [2048][256]
  //   [7M, 9M)       ek   f32 [64][2048][4]
  char* ws = (char*)d_ws;
  __bf16* Wt    = (__bf16*)ws;
  float*  wv2   = (float*)(ws + (512 << 10));
  float*  sumWp = (float*)(ws + (513 << 10));
  __bf16* Xbf   = (__bf16*)(ws + (1 << 20));
  float*  eqp   = (float*)(ws + (5ull << 20));
  float*  ekp   = (float*)(ws + (7ull << 20));

  prep_kernel<<<dim3(1281), 256, 0, stream>>>(
      Wq, Wk, wv, queries, Keys, Wt, Xbf, wv2, sumWp);
  proj_kernel<<<dim3(64, 8, 2), 256, 0, stream>>>(Xbf, Wt, eqp, ekp);
  score_kernel<<<dim3(2, 128, 4), 256, 0, stream>>>(
      eqp, (const float4*)ekp, wv2, sumWp, out);
}

// Round 6
// 114.158 us; speedup vs baseline: 1.0542x; 1.0353x over previous
//
#include <hip/hip_runtime.h>
#include <hip/hip_bf16.h>

// B=4, Q=K=512, D=512, H=256
#define HH 256
#define DD 512
#define MM 2048                       // B*Q == B*K flattened rows
#define CSCALE 2.8853900817779268f    // 2*log2(e), folded into W (linear)

typedef __bf16 bf16x8 __attribute__((ext_vector_type(8)));
typedef float floatx4 __attribute__((ext_vector_type(4)));

// ---------------------------------------------------------------------------
// prep: (a) blocks 0..255: transpose+scale Wq,Wk -> Wt[2][256][512] bf16
//       (b) block 256: wv2 = -2*wv, sumW = sum(wv)
//       (c) blocks 257..1280: convert queries||keys f32 -> Xbf bf16 [2M]
// ---------------------------------------------------------------------------
__global__ __launch_bounds__(256) void prep_kernel(
    const float* __restrict__ Wq, const float* __restrict__ Wk,
    const float* __restrict__ wv,
    const float* __restrict__ queries, const float* __restrict__ keys,
    __bf16* __restrict__ Wt, __bf16* __restrict__ Xbf,
    float* __restrict__ wv2, float* __restrict__ sumWp)
{
  const int bx = blockIdx.x;
  if (bx < 256) {
    const int mat  = bx >> 7;
    const int tile = bx & 127;
    const int kt = tile & 15;    // 512/32 k-tiles
    const int nt = tile >> 4;    // 256/32 n-tiles
    const float* __restrict__ W = mat ? Wk : Wq;
    __bf16* __restrict__ Wo = Wt + (size_t)mat * HH * DD;
    __shared__ float lds[32][33];
    const int i = threadIdx.x >> 5;   // 0..7
    const int j = threadIdx.x & 31;   // 0..31
    const int k0 = kt * 32, n0 = nt * 32;
#pragma unroll
    for (int p = 0; p < 4; ++p)
      lds[i + p * 8][j] = W[(k0 + i + p * 8) * HH + n0 + j];
    __syncthreads();
#pragma unroll
    for (int p = 0; p < 4; ++p) {
      const int n = i + p * 8;
      Wo[(n0 + n) * DD + k0 + j] = (__bf16)(lds[j][n] * CSCALE);
    }
  } else if (bx == 256) {
    __shared__ float red[256];
    const int t = threadIdx.x;
    float w = wv[t];
    wv2[t] = -2.0f * w;
    red[t] = w;
    __syncthreads();
    for (int s = 128; s > 0; s >>= 1) {
      if (t < s) red[t] += red[t + s];
      __syncthreads();
    }
    if (t == 0) *sumWp = red[0];
  } else {
    const int blk = bx - 257;                       // 0..1023
    const size_t dst = (size_t)blk * 2048 + threadIdx.x * 8;
    const float* __restrict__ src =
        (blk < 512) ? (queries + dst) : (keys + dst - (size_t)1048576);
    float4 a = *(const float4*)(src);
    float4 b = *(const float4*)(src + 4);
    bf16x8 v;
    v[0] = (__bf16)a.x; v[1] = (__bf16)a.y; v[2] = (__bf16)a.z; v[3] = (__bf16)a.w;
    v[4] = (__bf16)b.x; v[5] = (__bf16)b.y; v[6] = (__bf16)b.z; v[7] = (__bf16)b.w;
    *(bf16x8*)(Xbf + dst) = v;
  }
}

// ---------------------------------------------------------------------------
// proj: P = Xbf(2048x512 bf16) @ Wt^T (bf16, prescaled by 2*log2e).
// Block = 4 waves: wave (tw, ks) computes 16x32 tile tw over K-half ks.
// LDS combine, then exp2 epilogue:
//   z==0: queries -> eq = exp2(qc) f32 [2048][256]
//   z==1: keys    -> ek = exp2(kc) f32 [64][2048][4] (h-quad packed)
// Fragment layouts (HW-verified rounds 1-5):
//   A: lane A[m=lane&15][k=(lane>>4)*8+j]; B: B[k=(lane>>4)*8+j][n=lane&15]
//   D: reg i -> row=(lane>>4)*4+i, col=lane&15
// ---------------------------------------------------------------------------
__global__ __launch_bounds__(256, 4) void proj_kernel(
    const __bf16* __restrict__ Xbf, const __bf16* __restrict__ Wt,
    float* __restrict__ eqp, float* __restrict__ ekp)
{
  const int w    = threadIdx.x >> 6;
  const int lane = threadIdx.x & 63;
  const int quad = lane >> 4;
  const int r    = lane & 15;
  const int tw = w & 1;        // which 16-row tile
  const int ks = w >> 1;       // which K half
  const bool is_k = (blockIdx.z != 0);
  const __bf16* __restrict__ X  = Xbf + (is_k ? (size_t)1048576 : 0);
  const __bf16* __restrict__ Wb = Wt + (is_k ? (size_t)HH * DD : 0);

  const int m0 = blockIdx.x * 32 + tw * 16;
  const int n0 = blockIdx.y * 32;

  floatx4 acc0 = {0.f, 0.f, 0.f, 0.f};
  floatx4 acc1 = {0.f, 0.f, 0.f, 0.f};
  const __bf16* arow = X + (size_t)(m0 + r) * DD + ks * 256 + quad * 8;
  const __bf16* b0   = Wb + (size_t)(n0 + r) * DD + ks * 256 + quad * 8;
  const __bf16* b1   = b0 + 16 * DD;

#pragma unroll
  for (int kk = 0; kk < 256; kk += 32) {
    bf16x8 af  = *(const bf16x8*)(arow + kk);
    bf16x8 bf0 = *(const bf16x8*)(b0 + kk);
    bf16x8 bf1 = *(const bf16x8*)(b1 + kk);
    acc0 = __builtin_amdgcn_mfma_f32_16x16x32_bf16(af, bf0, acc0, 0, 0, 0);
    acc1 = __builtin_amdgcn_mfma_f32_16x16x32_bf16(af, bf1, acc1, 0, 0, 0);
  }

  __shared__ float part[2][64][9];   // +1 pad: conflict-free combine
  if (ks == 1) {
#pragma unroll
    for (int i = 0; i < 4; ++i) {
      part[tw][lane][i]     = acc0[i];
      part[tw][lane][4 + i] = acc1[i];
    }
  }
  __syncthreads();
  if (ks == 0) {
#pragma unroll
    for (int i = 0; i < 4; ++i) {
      acc0[i] += part[tw][lane][i];
      acc1[i] += part[tw][lane][4 + i];
    }
    const int mrow = m0 + quad * 4;
    if (!is_k) {
#pragma unroll
      for (int i = 0; i < 4; ++i) {
        eqp[(size_t)(mrow + i) * HH + n0 + r] =
            __builtin_amdgcn_exp2f(acc0[i]);
        eqp[(size_t)(mrow + i) * HH + n0 + 16 + r] =
            __builtin_amdgcn_exp2f(acc1[i]);
      }
    } else {
      const int na = n0 + r, nb = n0 + 16 + r;
#pragma unroll
      for (int i = 0; i < 4; ++i) {
        ekp[((size_t)(na >> 2) * MM + (mrow + i)) * 4 + (na & 3)] =
            __builtin_amdgcn_exp2f(acc0[i]);
        ekp[((size_t)(nb >> 2) * MM + (mrow + i)) * 4 + (nb & 3)] =
            __builtin_amdgcn_exp2f(acc1[i]);
      }
    }
  }
}

// ---------------------------------------------------------------------------
// score: out[b,q,k] = sumW + sum_{quads} [n01*p23 + n23*p01] * rcp(p01*p23)
//   u_i = 1 + eq[q,h_i]*ek[k,h_i]; p01=u0*u1, p23=u2*u3
//   n01 = w'0*u1 + w'1*u0, n23 = w'2*u3 + w'3*u2, w' = -2*wv
// == sum_h wv[h]*tanh(q_h+k_h): ONE rcp per FOUR h-terms (exact algebra).
// u>=1 so p-products >=1 (no subnormals); if p01*p23 overflows to Inf,
// rcp->0 which is the correct limit (tanh->1 absorbed in sumW).
// 14 VALU + 1 trans per 4 terms = ~9 issue-cyc/wave-term.
// eq/w wave-uniform (s_load path, keeps VGPR low); ek one dwordx4 per 4h.
// TQ=2, grid (2,256,4)=2048 blocks -> 8 waves/SIMD for latency hiding.
// ---------------------------------------------------------------------------
__device__ __forceinline__ float quad_term(
    float4 ek4, const float* __restrict__ eqr,
    float w0, float w1, float w2, float w3, float acc)
{
  float u0 = fmaf(eqr[0], ek4.x, 1.0f);
  float u1 = fmaf(eqr[1], ek4.y, 1.0f);
  float u2 = fmaf(eqr[2], ek4.z, 1.0f);
  float u3 = fmaf(eqr[3], ek4.w, 1.0f);
  float p01 = u0 * u1;
  float p23 = u2 * u3;
  float n01 = fmaf(w1, u0, w0 * u1);
  float n23 = fmaf(w3, u2, w2 * u3);
  float N   = fmaf(n23, p01, n01 * p23);
  float r   = __builtin_amdgcn_rcpf(p01 * p23);
  return fmaf(N, r, acc);
}

__global__ __launch_bounds__(256) void score_kernel(
    const float* __restrict__ eqp, const float4* __restrict__ ekp,
    const float* __restrict__ wv2, const float* __restrict__ sumWp,
    float* __restrict__ out)
{
  const int t  = threadIdx.x;
  const int b  = blockIdx.z;
  const int k  = blockIdx.x * 256 + t;
  const int q0 = blockIdx.y * 2;
  const float sumW = *sumWp;

  const float4* __restrict__ kptr = ekp + (size_t)b * 512 + k;
  const float* __restrict__ qb = eqp + (size_t)(b * 512 + q0) * HH;

  float acc0 = 0.f, acc1 = 0.f;

#pragma unroll 4
  for (int hq = 0; hq < 64; ++hq) {
    float4 ek4 = kptr[(size_t)hq * MM];
    const float* wq = wv2 + hq * 4;                 // uniform -> s_load
    float w0 = wq[0], w1 = wq[1], w2 = wq[2], w3 = wq[3];
    acc0 = quad_term(ek4, qb + hq * 4,      w0, w1, w2, w3, acc0);
    acc1 = quad_term(ek4, qb + HH + hq * 4, w0, w1, w2, w3, acc1);
  }

  const size_t ob = ((size_t)(b * 512 + q0)) * 512 + blockIdx.x * 256 + t;
  out[ob]       = sumW + acc0;
  out[ob + 512] = sumW + acc1;
}

// ---------------------------------------------------------------------------
extern "C" void kernel_launch(void* const* d_in, const int* in_sizes, int n_in,
                              void* d_out, int out_size, void* d_ws, size_t ws_size,
                              hipStream_t stream) {
  (void)in_sizes; (void)n_in; (void)out_size; (void)ws_size;
  const float* queries = (const float*)d_in[0];
  const float* Keys    = (const float*)d_in[1];
  const float* Wq      = (const float*)d_in[2];
  const float* Wk      = (const float*)d_in[3];
  const float* wv      = (const float*)d_in[4];
  float* out = (float*)d_out;

  // ws layout (~9 MB of the 256 MB workspace):
  //   [0, 512K)      Wt   bf16 [2][256][512]
  //   [512K, +1K)    wv2  f32 [256]  (= -2*wv)
  //   [513K, +4)     sumW
  //   [1M, 5M)       Xbf  bf16 [2][2048][512]  (queries||keys, converted)
  //   [5M, 7M)       eq   f32 [2048][256]
  //   [7M, 9M)       ek   f32 [64][2048][4]
  char* ws = (char*)d_ws;
  __bf16* Wt    = (__bf16*)ws;
  float*  wv2   = (float*)(ws + (512 << 10));
  float*  sumWp = (float*)(ws + (513 << 10));
  __bf16* Xbf   = (__bf16*)(ws + (1 << 20));
  float*  eqp   = (float*)(ws + (5ull << 20));
  float*  ekp   = (float*)(ws + (7ull << 20));

  prep_kernel<<<dim3(1281), 256, 0, stream>>>(
      Wq, Wk, wv, queries, Keys, Wt, Xbf, wv2, sumWp);
  proj_kernel<<<dim3(64, 8, 2), 256, 0, stream>>>(Xbf, Wt, eqp, ekp);
  score_kernel<<<dim3(2, 256, 4), 256, 0, stream>>>(
      eqp, (const float4*)ekp, wv2, sumWp, out);
}

// Round 7
// 113.047 us; speedup vs baseline: 1.0645x; 1.0098x over previous
//
#include <hip/hip_runtime.h>
#include <hip/hip_bf16.h>

// B=4, Q=K=512, D=512, H=256
#define HH 256
#define DD 512
#define MM 2048                       // B*Q == B*K flattened rows
#define CSCALE 2.8853900817779268f    // 2*log2(e), folded into W (linear)

typedef __bf16 bf16x8 __attribute__((ext_vector_type(8)));
typedef float floatx4 __attribute__((ext_vector_type(4)));

// ---------------------------------------------------------------------------
// prep: (a) blocks 0..255: transpose+scale Wq,Wk -> Wt[2][256][512] bf16
//       (b) block 256: wv2 = -2*wv, sumW = sum(wv)
//       (c) blocks 257..1280: convert queries||keys f32 -> Xbf bf16 [2M]
// ---------------------------------------------------------------------------
__global__ __launch_bounds__(256) void prep_kernel(
    const float* __restrict__ Wq, const float* __restrict__ Wk,
    const float* __restrict__ wv,
    const float* __restrict__ queries, const float* __restrict__ keys,
    __bf16* __restrict__ Wt, __bf16* __restrict__ Xbf,
    float* __restrict__ wv2, float* __restrict__ sumWp)
{
  const int bx = blockIdx.x;
  if (bx < 256) {
    const int mat  = bx >> 7;
    const int tile = bx & 127;
    const int kt = tile & 15;    // 512/32 k-tiles
    const int nt = tile >> 4;    // 256/32 n-tiles
    const float* __restrict__ W = mat ? Wk : Wq;
    __bf16* __restrict__ Wo = Wt + (size_t)mat * HH * DD;
    __shared__ float lds[32][33];
    const int i = threadIdx.x >> 5;   // 0..7
    const int j = threadIdx.x & 31;   // 0..31
    const int k0 = kt * 32, n0 = nt * 32;
#pragma unroll
    for (int p = 0; p < 4; ++p)
      lds[i + p * 8][j] = W[(k0 + i + p * 8) * HH + n0 + j];
    __syncthreads();
#pragma unroll
    for (int p = 0; p < 4; ++p) {
      const int n = i + p * 8;
      Wo[(n0 + n) * DD + k0 + j] = (__bf16)(lds[j][n] * CSCALE);
    }
  } else if (bx == 256) {
    __shared__ float red[256];
    const int t = threadIdx.x;
    float w = wv[t];
    wv2[t] = -2.0f * w;
    red[t] = w;
    __syncthreads();
    for (int s = 128; s > 0; s >>= 1) {
      if (t < s) red[t] += red[t + s];
      __syncthreads();
    }
    if (t == 0) *sumWp = red[0];
  } else {
    const int blk = bx - 257;                       // 0..1023
    const size_t dst = (size_t)blk * 2048 + threadIdx.x * 8;
    const float* __restrict__ src =
        (blk < 512) ? (queries + dst) : (keys + dst - (size_t)1048576);
    float4 a = *(const float4*)(src);
    float4 b = *(const float4*)(src + 4);
    bf16x8 v;
    v[0] = (__bf16)a.x; v[1] = (__bf16)a.y; v[2] = (__bf16)a.z; v[3] = (__bf16)a.w;
    v[4] = (__bf16)b.x; v[5] = (__bf16)b.y; v[6] = (__bf16)b.z; v[7] = (__bf16)b.w;
    *(bf16x8*)(Xbf + dst) = v;
  }
}

// ---------------------------------------------------------------------------
// proj: P = Xbf(2048x512 bf16) @ Wt^T (bf16, prescaled by 2*log2e).
// Block = 4 waves: wave (tw, ks) computes 16x32 tile tw over K-half ks.
// LDS combine, then exp2 epilogue:
//   z==0: queries -> eq = exp2(qc) f32  [2048][256]
//   z==1: keys    -> ek = exp2(kc) BF16 [64][2048][4] (h-quad packed, 1 MB:
//         halves score's L2 stream; bf16 keeps f32 exponent range)
// Fragment layouts (HW-verified rounds 1-6):
//   A: lane A[m=lane&15][k=(lane>>4)*8+j]; B: B[k=(lane>>4)*8+j][n=lane&15]
//   D: reg i -> row=(lane>>4)*4+i, col=lane&15
// ---------------------------------------------------------------------------
__global__ __launch_bounds__(256, 4) void proj_kernel(
    const __bf16* __restrict__ Xbf, const __bf16* __restrict__ Wt,
    float* __restrict__ eqp, __bf16* __restrict__ ekb)
{
  const int w    = threadIdx.x >> 6;
  const int lane = threadIdx.x & 63;
  const int quad = lane >> 4;
  const int r    = lane & 15;
  const int tw = w & 1;        // which 16-row tile
  const int ks = w >> 1;       // which K half
  const bool is_k = (blockIdx.z != 0);
  const __bf16* __restrict__ X  = Xbf + (is_k ? (size_t)1048576 : 0);
  const __bf16* __restrict__ Wb = Wt + (is_k ? (size_t)HH * DD : 0);

  const int m0 = blockIdx.x * 32 + tw * 16;
  const int n0 = blockIdx.y * 32;

  floatx4 acc0 = {0.f, 0.f, 0.f, 0.f};
  floatx4 acc1 = {0.f, 0.f, 0.f, 0.f};
  const __bf16* arow = X + (size_t)(m0 + r) * DD + ks * 256 + quad * 8;
  const __bf16* b0   = Wb + (size_t)(n0 + r) * DD + ks * 256 + quad * 8;
  const __bf16* b1   = b0 + 16 * DD;

#pragma unroll
  for (int kk = 0; kk < 256; kk += 32) {
    bf16x8 af  = *(const bf16x8*)(arow + kk);
    bf16x8 bf0 = *(const bf16x8*)(b0 + kk);
    bf16x8 bf1 = *(const bf16x8*)(b1 + kk);
    acc0 = __builtin_amdgcn_mfma_f32_16x16x32_bf16(af, bf0, acc0, 0, 0, 0);
    acc1 = __builtin_amdgcn_mfma_f32_16x16x32_bf16(af, bf1, acc1, 0, 0, 0);
  }

  __shared__ float part[2][64][9];   // +1 pad: conflict-free combine
  if (ks == 1) {
#pragma unroll
    for (int i = 0; i < 4; ++i) {
      part[tw][lane][i]     = acc0[i];
      part[tw][lane][4 + i] = acc1[i];
    }
  }
  __syncthreads();
  if (ks == 0) {
#pragma unroll
    for (int i = 0; i < 4; ++i) {
      acc0[i] += part[tw][lane][i];
      acc1[i] += part[tw][lane][4 + i];
    }
    const int mrow = m0 + quad * 4;
    if (!is_k) {
#pragma unroll
      for (int i = 0; i < 4; ++i) {
        eqp[(size_t)(mrow + i) * HH + n0 + r] =
            __builtin_amdgcn_exp2f(acc0[i]);
        eqp[(size_t)(mrow + i) * HH + n0 + 16 + r] =
            __builtin_amdgcn_exp2f(acc1[i]);
      }
    } else {
      const int na = n0 + r, nb = n0 + 16 + r;
#pragma unroll
      for (int i = 0; i < 4; ++i) {
        ekb[((size_t)(na >> 2) * MM + (mrow + i)) * 4 + (na & 3)] =
            (__bf16)__builtin_amdgcn_exp2f(acc0[i]);
        ekb[((size_t)(nb >> 2) * MM + (mrow + i)) * 4 + (nb & 3)] =
            (__bf16)__builtin_amdgcn_exp2f(acc1[i]);
      }
    }
  }
}

// ---------------------------------------------------------------------------
// score: out[b,q,k] = sumW + sum_{quads} [n01*p23 + n23*p01] * rcp(p01*p23)
//   u_i = 1 + eq[q,h_i]*ek[k,h_i]; p01=u0*u1, p23=u2*u3
//   n01 = w'0*u1 + w'1*u0, n23 = w'2*u3 + w'3*u2, w' = -2*wv
// == sum_h wv[h]*tanh(q_h+k_h): ONE rcp per FOUR h-terms (exact algebra).
// ek stream is bf16 (dwordx2/lane/4h): 256 MB total L2 traffic (halved vs
// f32 — R3/R4/R6 all plateaued at ~38 us = 13.5 TB/s on the 512 MB stream).
// Unpack = 2 shl + 2 and per 4h, shared by both q-rows (~0.5 cyc/term).
// 9.5 issue-cyc/wave-term; eq/w wave-uniform (s_load path, VGPR stays low).
// TQ=2, grid (2,256,4)=2048 blocks -> 8 waves/SIMD.
// ---------------------------------------------------------------------------
__device__ __forceinline__ float quad_term(
    float ek0, float ek1, float ek2, float ek3,
    const float* __restrict__ eqr,
    float w0, float w1, float w2, float w3, float acc)
{
  float u0 = fmaf(eqr[0], ek0, 1.0f);
  float u1 = fmaf(eqr[1], ek1, 1.0f);
  float u2 = fmaf(eqr[2], ek2, 1.0f);
  float u3 = fmaf(eqr[3], ek3, 1.0f);
  float p01 = u0 * u1;
  float p23 = u2 * u3;
  float n01 = fmaf(w1, u0, w0 * u1);
  float n23 = fmaf(w3, u2, w2 * u3);
  float N   = fmaf(n23, p01, n01 * p23);
  float r   = __builtin_amdgcn_rcpf(p01 * p23);
  return fmaf(N, r, acc);
}

__global__ __launch_bounds__(256) void score_kernel(
    const float* __restrict__ eqp, const uint2* __restrict__ ekb,
    const float* __restrict__ wv2, const float* __restrict__ sumWp,
    float* __restrict__ out)
{
  const int t  = threadIdx.x;
  const int b  = blockIdx.z;
  const int k  = blockIdx.x * 256 + t;
  const int q0 = blockIdx.y * 2;
  const float sumW = *sumWp;

  const uint2* __restrict__ kptr = ekb + (size_t)b * 512 + k;
  const float* __restrict__ qb = eqp + (size_t)(b * 512 + q0) * HH;

  float acc0 = 0.f, acc1 = 0.f;

#pragma unroll 4
  for (int hq = 0; hq < 64; ++hq) {
    uint2 kp = kptr[(size_t)hq * MM];
    float ek0 = __uint_as_float(kp.x << 16);
    float ek1 = __uint_as_float(kp.x & 0xffff0000u);
    float ek2 = __uint_as_float(kp.y << 16);
    float ek3 = __uint_as_float(kp.y & 0xffff0000u);
    const float* wq = wv2 + hq * 4;                 // uniform -> s_load
    float w0 = wq[0], w1 = wq[1], w2 = wq[2], w3 = wq[3];
    acc0 = quad_term(ek0, ek1, ek2, ek3, qb + hq * 4,      w0, w1, w2, w3, acc0);
    acc1 = quad_term(ek0, ek1, ek2, ek3, qb + HH + hq * 4, w0, w1, w2, w3, acc1);
  }

  const size_t ob = ((size_t)(b * 512 + q0)) * 512 + blockIdx.x * 256 + t;
  out[ob]       = sumW + acc0;
  out[ob + 512] = sumW + acc1;
}

// ---------------------------------------------------------------------------
extern "C" void kernel_launch(void* const* d_in, const int* in_sizes, int n_in,
                              void* d_out, int out_size, void* d_ws, size_t ws_size,
                              hipStream_t stream) {
  (void)in_sizes; (void)n_in; (void)out_size; (void)ws_size;
  const float* queries = (const float*)d_in[0];
  const float* Keys    = (const float*)d_in[1];
  const float* Wq      = (const float*)d_in[2];
  const float* Wk      = (const float*)d_in[3];
  const float* wv      = (const float*)d_in[4];
  float* out = (float*)d_out;

  // ws layout (~8 MB of the 256 MB workspace):
  //   [0, 512K)      Wt   bf16 [2][256][512]
  //   [512K, +1K)    wv2  f32 [256]  (= -2*wv)
  //   [513K, +4)     sumW
  //   [1M, 5M)       Xbf  bf16 [2][2048][512]  (queries||keys, converted)
  //   [5M, 7M)       eq   f32  [2048][256]
  //   [7M, 8M)       ekb  bf16 [64][2048][4]   (1 MB — L2-resident per XCD)
  char* ws = (char*)d_ws;
  __bf16* Wt    = (__bf16*)ws;
  float*  wv2   = (float*)(ws + (512 << 10));
  float*  sumWp = (float*)(ws + (513 << 10));
  __bf16* Xbf   = (__bf16*)(ws + (1 << 20));
  float*  eqp   = (float*)(ws + (5ull << 20));
  __bf16* ekb   = (__bf16*)(ws + (7ull << 20));

  prep_kernel<<<dim3(1281), 256, 0, stream>>>(
      Wq, Wk, wv, queries, Keys, Wt, Xbf, wv2, sumWp);
  proj_kernel<<<dim3(64, 8, 2), 256, 0, stream>>>(Xbf, Wt, eqp, ekb);
  score_kernel<<<dim3(2, 256, 4), 256, 0, stream>>>(
      eqp, (const uint2*)ekb, wv2, sumWp, out);
}

// Round 8
// 112.869 us; speedup vs baseline: 1.0662x; 1.0016x over previous
//
#include <hip/hip_runtime.h>
#include <hip/hip_bf16.h>

// B=4, Q=K=512, D=512, H=256
#define HH 256
#define DD 512
#define MM 2048                       // B*Q == B*K flattened rows
#define CSCALE 2.8853900817779268f    // 2*log2(e), folded into W (linear)

typedef __bf16 bf16x8 __attribute__((ext_vector_type(8)));
typedef float floatx4 __attribute__((ext_vector_type(4)));

// ---------------------------------------------------------------------------
// prep: (a) blocks 0..255: transpose+scale Wq,Wk -> Wt[2][256][512] bf16
//       (b) block 256: wv2 = -2*wv, sumW = sum(wv)
//       (c) blocks 257..1280: convert queries||keys f32 -> Xbf bf16 [2M]
// ---------------------------------------------------------------------------
__global__ __launch_bounds__(256) void prep_kernel(
    const float* __restrict__ Wq, const float* __restrict__ Wk,
    const float* __restrict__ wv,
    const float* __restrict__ queries, const float* __restrict__ keys,
    __bf16* __restrict__ Wt, __bf16* __restrict__ Xbf,
    float* __restrict__ wv2, float* __restrict__ sumWp)
{
  const int bx = blockIdx.x;
  if (bx < 256) {
    const int mat  = bx >> 7;
    const int tile = bx & 127;
    const int kt = tile & 15;    // 512/32 k-tiles
    const int nt = tile >> 4;    // 256/32 n-tiles
    const float* __restrict__ W = mat ? Wk : Wq;
    __bf16* __restrict__ Wo = Wt + (size_t)mat * HH * DD;
    __shared__ float lds[32][33];
    const int i = threadIdx.x >> 5;   // 0..7
    const int j = threadIdx.x & 31;   // 0..31
    const int k0 = kt * 32, n0 = nt * 32;
#pragma unroll
    for (int p = 0; p < 4; ++p)
      lds[i + p * 8][j] = W[(k0 + i + p * 8) * HH + n0 + j];
    __syncthreads();
#pragma unroll
    for (int p = 0; p < 4; ++p) {
      const int n = i + p * 8;
      Wo[(n0 + n) * DD + k0 + j] = (__bf16)(lds[j][n] * CSCALE);
    }
  } else if (bx == 256) {
    __shared__ float red[256];
    const int t = threadIdx.x;
    float w = wv[t];
    wv2[t] = -2.0f * w;
    red[t] = w;
    __syncthreads();
    for (int s = 128; s > 0; s >>= 1) {
      if (t < s) red[t] += red[t + s];
      __syncthreads();
    }
    if (t == 0) *sumWp = red[0];
  } else {
    const int blk = bx - 257;                       // 0..1023
    const size_t dst = (size_t)blk * 2048 + threadIdx.x * 8;
    const float* __restrict__ src =
        (blk < 512) ? (queries + dst) : (keys + dst - (size_t)1048576);
    float4 a = *(const float4*)(src);
    float4 b = *(const float4*)(src + 4);
    bf16x8 v;
    v[0] = (__bf16)a.x; v[1] = (__bf16)a.y; v[2] = (__bf16)a.z; v[3] = (__bf16)a.w;
    v[4] = (__bf16)b.x; v[5] = (__bf16)b.y; v[6] = (__bf16)b.z; v[7] = (__bf16)b.w;
    *(bf16x8*)(Xbf + dst) = v;
  }
}

// ---------------------------------------------------------------------------
// proj: P = Xbf(2048x512 bf16) @ Wt^T (bf16, prescaled by 2*log2e).
// Block = 4 waves: wave (tw, ks) computes 16x32 tile tw over K-half ks.
// LDS combine, then exp2 epilogue:
//   z==0: queries -> eq = exp2(qc) f32  [2048][256]
//   z==1: keys    -> ek = exp2(kc) BF16 [64][2048][4] (h-quad packed, 1 MB)
// Fragment layouts (HW-verified rounds 1-7):
//   A: lane A[m=lane&15][k=(lane>>4)*8+j]; B: B[k=(lane>>4)*8+j][n=lane&15]
//   D: reg i -> row=(lane>>4)*4+i, col=lane&15
// ---------------------------------------------------------------------------
__global__ __launch_bounds__(256, 4) void proj_kernel(
    const __bf16* __restrict__ Xbf, const __bf16* __restrict__ Wt,
    float* __restrict__ eqp, __bf16* __restrict__ ekb)
{
  const int w    = threadIdx.x >> 6;
  const int lane = threadIdx.x & 63;
  const int quad = lane >> 4;
  const int r    = lane & 15;
  const int tw = w & 1;        // which 16-row tile
  const int ks = w >> 1;       // which K half
  const bool is_k = (blockIdx.z != 0);
  const __bf16* __restrict__ X  = Xbf + (is_k ? (size_t)1048576 : 0);
  const __bf16* __restrict__ Wb = Wt + (is_k ? (size_t)HH * DD : 0);

  const int m0 = blockIdx.x * 32 + tw * 16;
  const int n0 = blockIdx.y * 32;

  floatx4 acc0 = {0.f, 0.f, 0.f, 0.f};
  floatx4 acc1 = {0.f, 0.f, 0.f, 0.f};
  const __bf16* arow = X + (size_t)(m0 + r) * DD + ks * 256 + quad * 8;
  const __bf16* b0   = Wb + (size_t)(n0 + r) * DD + ks * 256 + quad * 8;
  const __bf16* b1   = b0 + 16 * DD;

#pragma unroll
  for (int kk = 0; kk < 256; kk += 32) {
    bf16x8 af  = *(const bf16x8*)(arow + kk);
    bf16x8 bf0 = *(const bf16x8*)(b0 + kk);
    bf16x8 bf1 = *(const bf16x8*)(b1 + kk);
    acc0 = __builtin_amdgcn_mfma_f32_16x16x32_bf16(af, bf0, acc0, 0, 0, 0);
    acc1 = __builtin_amdgcn_mfma_f32_16x16x32_bf16(af, bf1, acc1, 0, 0, 0);
  }

  __shared__ float part[2][64][9];   // +1 pad: conflict-free combine
  if (ks == 1) {
#pragma unroll
    for (int i = 0; i < 4; ++i) {
      part[tw][lane][i]     = acc0[i];
      part[tw][lane][4 + i] = acc1[i];
    }
  }
  __syncthreads();
  if (ks == 0) {
#pragma unroll
    for (int i = 0; i < 4; ++i) {
      acc0[i] += part[tw][lane][i];
      acc1[i] += part[tw][lane][4 + i];
    }
    const int mrow = m0 + quad * 4;
    if (!is_k) {
#pragma unroll
      for (int i = 0; i < 4; ++i) {
        eqp[(size_t)(mrow + i) * HH + n0 + r] =
            __builtin_amdgcn_exp2f(acc0[i]);
        eqp[(size_t)(mrow + i) * HH + n0 + 16 + r] =
            __builtin_amdgcn_exp2f(acc1[i]);
      }
    } else {
      const int na = n0 + r, nb = n0 + 16 + r;
#pragma unroll
      for (int i = 0; i < 4; ++i) {
        ekb[((size_t)(na >> 2) * MM + (mrow + i)) * 4 + (na & 3)] =
            (__bf16)__builtin_amdgcn_exp2f(acc0[i]);
        ekb[((size_t)(nb >> 2) * MM + (mrow + i)) * 4 + (nb & 3)] =
            (__bf16)__builtin_amdgcn_exp2f(acc1[i]);
      }
    }
  }
}

// ---------------------------------------------------------------------------
// score: out[b,q,k] = sumW + sum_{quads} [n01*p23 + n23*p01] * rcp(p01*p23)
//   u_i = 1 + eq[q,h_i]*ek[k,h_i]; p01=u0*u1, p23=u2*u3
//   n01 = w'0*u1 + w'1*u0, n23 = w'2*u3 + w'3*u2, w' = -2*wv
// ONE rcp per FOUR h-terms (exact algebra; u>=1, Inf->rcp->0 correct limit).
//
// R8 change: uniform operands (eq 2 rows, wv2) move SMEM -> LDS. Rationale:
// R2-R7 score was pinned at ~37-45us with 112 SGPRs and 3 s_load_dwordx4 per
// iter; SMEM retires OOO on lgkmcnt alongside nothing else fine-grained ->
// coarse drains every batch. LDS same-address reads are broadcast
// (conflict-free), DS retires in-order -> fine lgkmcnt, SGPRs freed.
// ek stream stays bf16 coalesced (dwordx2/lane/4h).
// TQ=2, grid (2,256,4)=2048 blocks; launch_bounds(256,8) caps VGPR at 64
// so 8 waves/SIMD; unroll 2 keeps live ranges inside that budget.
// ---------------------------------------------------------------------------
__device__ __forceinline__ float quad_term(
    float ek0, float ek1, float ek2, float ek3,
    float4 e, float4 w, float acc)
{
  float u0 = fmaf(e.x, ek0, 1.0f);
  float u1 = fmaf(e.y, ek1, 1.0f);
  float u2 = fmaf(e.z, ek2, 1.0f);
  float u3 = fmaf(e.w, ek3, 1.0f);
  float p01 = u0 * u1;
  float p23 = u2 * u3;
  float n01 = fmaf(w.y, u0, w.x * u1);
  float n23 = fmaf(w.w, u2, w.z * u3);
  float N   = fmaf(n23, p01, n01 * p23);
  float r   = __builtin_amdgcn_rcpf(p01 * p23);
  return fmaf(N, r, acc);
}

__global__ __launch_bounds__(256, 8) void score_kernel(
    const float* __restrict__ eqp, const uint2* __restrict__ ekb,
    const float* __restrict__ wv2, const float* __restrict__ sumWp,
    float* __restrict__ out)
{
  __shared__ __align__(16) float eqs[2][256];
  __shared__ __align__(16) float wvs[256];

  const int t  = threadIdx.x;
  const int b  = blockIdx.z;
  const int k  = blockIdx.x * 256 + t;
  const int q0 = blockIdx.y * 2;

  // Stage uniform operands: 2 eq rows (2 KB) + wv2 (1 KB), coalesced.
  {
    const float2* __restrict__ src =
        (const float2*)(eqp + (size_t)(b * 512 + q0) * HH);
    ((float2*)eqs)[t] = src[t];      // 512 floats = rows q0, q0+1
    wvs[t] = wv2[t];
  }
  const float sumW = *sumWp;
  __syncthreads();

  const uint2* __restrict__ kptr = ekb + (size_t)b * 512 + k;

  float acc0 = 0.f, acc1 = 0.f;

#pragma unroll 2
  for (int hq = 0; hq < 64; ++hq) {
    uint2 kp = kptr[(size_t)hq * MM];
    float4 e0 = *(const float4*)&eqs[0][hq * 4];   // ds_read_b128 broadcast
    float4 e1 = *(const float4*)&eqs[1][hq * 4];   // ds_read_b128 broadcast
    float4 w4 = *(const float4*)&wvs[hq * 4];      // ds_read_b128 broadcast
    float ek0 = __uint_as_float(kp.x << 16);
    float ek1 = __uint_as_float(kp.x & 0xffff0000u);
    float ek2 = __uint_as_float(kp.y << 16);
    float ek3 = __uint_as_float(kp.y & 0xffff0000u);
    acc0 = quad_term(ek0, ek1, ek2, ek3, e0, w4, acc0);
    acc1 = quad_term(ek0, ek1, ek2, ek3, e1, w4, acc1);
  }

  const size_t ob = ((size_t)(b * 512 + q0)) * 512 + blockIdx.x * 256 + t;
  out[ob]       = sumW + acc0;
  out[ob + 512] = sumW + acc1;
}

// ---------------------------------------------------------------------------
extern "C" void kernel_launch(void* const* d_in, const int* in_sizes, int n_in,
                              void* d_out, int out_size, void* d_ws, size_t ws_size,
                              hipStream_t stream) {
  (void)in_sizes; (void)n_in; (void)out_size; (void)ws_size;
  const float* queries = (const float*)d_in[0];
  const float* Keys    = (const float*)d_in[1];
  const float* Wq      = (const float*)d_in[2];
  const float* Wk      = (const float*)d_in[3];
  const float* wv      = (const float*)d_in[4];
  float* out = (float*)d_out;

  // ws layout (~8 MB of the 256 MB workspace):
  //   [0, 512K)      Wt   bf16 [2][256][512]
  //   [512K, +1K)    wv2  f32 [256]  (= -2*wv)
  //   [513K, +4)     sumW
  //   [1M, 5M)       Xbf  bf16 [2][2048][512]  (queries||keys, converted)
  //   [5M, 7M)       eq   f32  [2048][256]
  //   [7M, 8M)       ekb  bf16 [64][2048][4]   (1 MB — L2-resident per XCD)
  char* ws = (char*)d_ws;
  __bf16* Wt    = (__bf16*)ws;
  float*  wv2   = (float*)(ws + (512 << 10));
  float*  sumWp = (float*)(ws + (513 << 10));
  __bf16* Xbf   = (__bf16*)(ws + (1 << 20));
  float*  eqp   = (float*)(ws + (5ull << 20));
  __bf16* ekb   = (__bf16*)(ws + (7ull << 20));

  prep_kernel<<<dim3(1281), 256, 0, stream>>>(
      Wq, Wk, wv, queries, Keys, Wt, Xbf, wv2, sumWp);
  proj_kernel<<<dim3(64, 8, 2), 256, 0, stream>>>(Xbf, Wt, eqp, ekb);
  score_kernel<<<dim3(2, 256, 4), 256, 0, stream>>>(
      eqp, (const uint2*)ekb, wv2, sumWp, out);
}